// Round 27
// baseline (88.421 us; speedup 1.0000x reference)
//
#include <hip/hip_runtime.h>

#define N_NODES 50000
#define N_EDGES 600000
#define DIM 128
#define WGN (256 * 128 / 8)                   // 4096 granules of 8 bf16
#define GEMM_PAIRS ((N_NODES + 63) / 64)      // 782 node-tiles (x2 j-halves)
#define K1_BLOCKS (GEMM_PAIRS * 3)            // 2346: {g,g,p1} per group
#define ZERO_BLOCKS ((N_NODES + 255) / 256)   // 196
#define BCAP 64                               // bucket capacity (max deg ~35)
#define BINS 98                               // dst>>9 -> 98 bins of 512 nodes
#define BINCAP 8192                           // edges per bin (avg 6122 + 26σ)
#define P1_BLOCKS ((N_EDGES + 1023) / 1024)   // 586

typedef __attribute__((ext_vector_type(8))) short short8;
typedef __attribute__((ext_vector_type(4))) float f32x4;

__device__ __forceinline__ unsigned bf16rne(float f) {
  unsigned x = __float_as_uint(f);
  x += 0x7fffu + ((x >> 16) & 1u);
  return x >> 16;
}

__device__ __forceinline__ uint2 pack4(float4 v) {
  uint2 o;
  o.x = bf16rne(v.x) | (bf16rne(v.y) << 16);
  o.y = bf16rne(v.z) | (bf16rne(v.w) << 16);
  return o;
}

__device__ __forceinline__ void fma8(float* a, uint4 v, float w) {
  a[0] += __uint_as_float(v.x << 16) * w;
  a[1] += __uint_as_float(v.x & 0xffff0000u) * w;
  a[2] += __uint_as_float(v.y << 16) * w;
  a[3] += __uint_as_float(v.y & 0xffff0000u) * w;
  a[4] += __uint_as_float(v.z << 16) * w;
  a[5] += __uint_as_float(v.z & 0xffff0000u) * w;
  a[6] += __uint_as_float(v.w << 16) * w;
  a[7] += __uint_as_float(v.w & 0xffff0000u) * w;
}

// ---------------------------------------------------------------------------
// K0: deg = 0, gcnt = 0, wtS fragment pack (tiny).
// ---------------------------------------------------------------------------
__global__ __launch_bounds__(256) void k_zero_wts(
    int* __restrict__ deg, int* __restrict__ gcnt,
    const float* __restrict__ Wf, uint4* __restrict__ wtS) {
  int gid = blockIdx.x * 256 + threadIdx.x;
  if (gid < N_NODES) deg[gid] = 0;
  if (gid < BINS) gcnt[gid] = 0;
  if (gid < WGN) {
    int j = gid >> 4, cb = gid & 15;
    int jr = (j < 128) ? j : (j - 128);
    int c0 = ((j < 128) ? 0 : 128) + cb * 8;
    const float4* s = reinterpret_cast<const float4*>(Wf + (size_t)jr * 256 + c0);
    uint2 lo = pack4(s[0]);
    uint2 hi = pack4(s[1]);
    int jb = j >> 4, l16 = j & 15, ks = cb >> 2, lg = cb & 3;
    wtS[((jb * 4 + ks) * 64) + lg * 16 + l16] = make_uint4(lo.x, lo.y, hi.x, hi.y);
  }
}

// ---------------------------------------------------------------------------
// K1: STRIPED gemm + P1-binning, period 3 {g,g,p1}.
// P1 (r27): block bins its 1024 edges into 98 coarse bins (dst>>9) via LDS
// ranks; per-bin global base via ONE atomicAdd; writes GROUPED by bin
// (~83B contiguous per bin per block -> near-full-line writes). This
// replaces the 600K cross-XCD scattered 4B writes (the invariant ~41us
// wall: partial lines from all 8 XCDs never merge in non-coherent L2s).
// gemm (subs 0,1): unchanged r25 body (A from f32 coalesced + in-reg cvt
// -> swizzled LDS; W via wtS fragment blocks; packed 8B epilogue).
// ---------------------------------------------------------------------------
__global__ __launch_bounds__(256) void k_gemm_p1(
    const int* __restrict__ dst, const int* __restrict__ src,
    const float* __restrict__ ew, int* __restrict__ gcnt,
    uint2* __restrict__ binbuf,
    const float* __restrict__ nf, const uint4* __restrict__ wtS,
    const float* __restrict__ bias,
    unsigned short* __restrict__ y1, unsigned short* __restrict__ y2) {
  __shared__ char As[16384];
  const int grp = blockIdx.x / 3;
  const int sub = blockIdx.x % 3;
  const int tid = threadIdx.x;

  if (sub == 2) {
    // ---- P1: bin 1024 edges by dst>>9 with grouped writes ----
    if (grp >= P1_BLOCKS) return;
    int* lcnt = reinterpret_cast<int*>(As);           // 98 ints
    int* lbase = reinterpret_cast<int*>(As + 512);    // 98 ints
    if (tid < BINS) lcnt[tid] = 0;
    __syncthreads();

    const int e0 = grp * 1024 + tid;
    int d4[4], r4[4];
    unsigned rec4[4];
    bool v4[4];
#pragma unroll
    for (int k = 0; k < 4; ++k) {
      int e = e0 + k * 256;
      v4[k] = (e < N_EDGES);
      d4[k] = 0; rec4[k] = 0; r4[k] = 0;
      if (v4[k]) {
        d4[k] = dst[e];
        unsigned wq = (unsigned)rintf(ew[e] * 65535.0f);
        rec4[k] = (unsigned)src[e] | (wq << 16);
        r4[k] = atomicAdd(&lcnt[d4[k] >> 9], 1);
      }
    }
    __syncthreads();
    if (tid < BINS) lbase[tid] = atomicAdd(&gcnt[tid], lcnt[tid]);
    __syncthreads();
#pragma unroll
    for (int k = 0; k < 4; ++k) {
      if (v4[k]) {
        int bin = d4[k] >> 9;
        binbuf[(size_t)bin * BINCAP + lbase[bin] + r4[k]] =
            make_uint2(rec4[k], (unsigned)d4[k]);
      }
    }
    return;
  }

  // ---- gemm: 64 nodes x 128 j (jsel half), r25 body ----
  const int node0 = grp * 64;
  const int jsel = sub;               // 0 -> Y1, 1 -> Y2+bias

#pragma unroll
  for (int i = 0; i < 8; ++i) {
    int G = tid + i * 256;
    int r = G >> 5, c = G & 31;
    int node = node0 + r;
    if (node > N_NODES - 1) node = N_NODES - 1;   // tail: masked at store
    float4 v = *reinterpret_cast<const float4*>(nf + (size_t)node * DIM + c * 4);
    uint2 p = pack4(v);
    int g = c >> 1, half = c & 1;
    *reinterpret_cast<uint2*>(As + r * 256 + ((g ^ (r & 7)) * 16) + half * 8) = p;
  }
  __syncthreads();

  const int lane = tid & 63;
  const int wv = tid >> 6;
  const int l16 = lane & 15, lg = lane >> 4;

  f32x4 acc[4][2] = {};
#pragma unroll
  for (int ks = 0; ks < 4; ++ks) {
    short8 anf[4], awt[2];
#pragma unroll
    for (int m = 0; m < 4; ++m) {
      int r = m * 16 + l16;
      int g = ks * 4 + lg;
      anf[m] = *reinterpret_cast<const short8*>(As + r * 256 + ((g ^ (r & 7)) * 16));
    }
#pragma unroll
    for (int n = 0; n < 2; ++n) {
      int jb = jsel * 8 + wv * 2 + n;
      const uint4* fp = wtS + (jb * 4 + ks) * 64 + lane;
      uint4 v = *fp;
      awt[n] = *reinterpret_cast<const short8*>(&v);
    }
#pragma unroll
    for (int m = 0; m < 4; ++m)
#pragma unroll
      for (int n = 0; n < 2; ++n)
        acc[m][n] = __builtin_amdgcn_mfma_f32_16x16x32_bf16(awt[n], anf[m], acc[m][n], 0, 0, 0);
  }

  unsigned short* yb = jsel ? y2 : y1;
#pragma unroll
  for (int n = 0; n < 2; ++n) {
    int jb = (wv * 2 + n) * 16 + lg * 4;
    float4 bv = make_float4(0.f, 0.f, 0.f, 0.f);
    if (jsel) bv = *reinterpret_cast<const float4*>(bias + jb);
#pragma unroll
    for (int m = 0; m < 4; ++m) {
      int node = node0 + m * 16 + l16;
      if (node >= N_NODES) continue;
      uint2 st;
      st.x = bf16rne(acc[m][n][0] + bv.x) | (bf16rne(acc[m][n][1] + bv.y) << 16);
      st.y = bf16rne(acc[m][n][2] + bv.z) | (bf16rne(acc[m][n][3] + bv.w) << 16);
      *reinterpret_cast<uint2*>(yb + (size_t)node * 128 + jb) = st;
    }
  }
}

// ---------------------------------------------------------------------------
// K2: P2 — one block per bin scatters its edges into final buckets.
// Bin's deg (2KB) + bucket (128KB) region is touched by ONE block = one
// XCD = one L2 -> partial-line writes merge in L2, evict as full lines.
// ---------------------------------------------------------------------------
__global__ __launch_bounds__(256) void k_p2(
    const int* __restrict__ gcnt, const uint2* __restrict__ binbuf,
    int* __restrict__ deg, unsigned* __restrict__ srcw) {
  const int b = blockIdx.x;
  const int n = gcnt[b];
  const uint2* bb = binbuf + (size_t)b * BINCAP;
  for (int i = threadIdx.x; i < n; i += 256) {
    uint2 rec = bb[i];
    int d = (int)rec.y;
    int rk = atomicAdd(&deg[d], 1);
    srcw[d * BCAP + rk] = rec.x;
  }
}

// ---------------------------------------------------------------------------
// K3: gather-final over padded buckets (unchanged).
// out[n] = (sum_e w_e * Y1[src_e]) / max(deg,1) + Y2[n]   (f32 write)
// ---------------------------------------------------------------------------
__global__ __launch_bounds__(256) void k_gather(
    const uint4* __restrict__ y1q, const uint4* __restrict__ y2q,
    const int* __restrict__ deg, const unsigned* __restrict__ srcw,
    float4* __restrict__ out4) {
  int node = blockIdx.x * 4 + (threadIdx.x >> 6);
  int lane = threadIdx.x & 63;
  int g = lane >> 3;
  int c = lane & 7;
  int dg = deg[node];
  const unsigned* bucket = srcw + (size_t)node * BCAP;

  float a[16];
#pragma unroll
  for (int k = 0; k < 16; ++k) a[k] = 0.f;

  for (int j = g; j < dg; j += 8) {
    unsigned q = bucket[j];
    float w = (float)(q >> 16) * (1.0f / 65535.0f);
    const uint4* rp = y1q + (size_t)(q & 0xffffu) * 16 + c * 2;
    uint4 v0 = rp[0];
    uint4 v1 = rp[1];
    fma8(a, v0, w);
    fma8(a + 8, v1, w);
  }
#pragma unroll
  for (int k = 0; k < 16; ++k) {
    a[k] += __shfl_xor(a[k], 8);
    a[k] += __shfl_xor(a[k], 16);
    a[k] += __shfl_xor(a[k], 32);
  }
  if (g == 0) {
    float inv = 1.0f / (float)max(dg, 1);
    uint4 u0 = y2q[(size_t)node * 16 + c * 2];
    uint4 u1 = y2q[(size_t)node * 16 + c * 2 + 1];
    float4 o0, o1, o2, o3;
    o0.x = a[0] * inv + __uint_as_float(u0.x << 16);
    o0.y = a[1] * inv + __uint_as_float(u0.x & 0xffff0000u);
    o0.z = a[2] * inv + __uint_as_float(u0.y << 16);
    o0.w = a[3] * inv + __uint_as_float(u0.y & 0xffff0000u);
    o1.x = a[4] * inv + __uint_as_float(u0.z << 16);
    o1.y = a[5] * inv + __uint_as_float(u0.z & 0xffff0000u);
    o1.z = a[6] * inv + __uint_as_float(u0.w << 16);
    o1.w = a[7] * inv + __uint_as_float(u0.w & 0xffff0000u);
    o2.x = a[8] * inv + __uint_as_float(u1.x << 16);
    o2.y = a[9] * inv + __uint_as_float(u1.x & 0xffff0000u);
    o2.z = a[10] * inv + __uint_as_float(u1.y << 16);
    o2.w = a[11] * inv + __uint_as_float(u1.y & 0xffff0000u);
    o3.x = a[12] * inv + __uint_as_float(u1.z << 16);
    o3.y = a[13] * inv + __uint_as_float(u1.z & 0xffff0000u);
    o3.z = a[14] * inv + __uint_as_float(u1.w << 16);
    o3.w = a[15] * inv + __uint_as_float(u1.w & 0xffff0000u);
    float4* op = out4 + (size_t)node * 32 + c * 4;
    op[0] = o0; op[1] = o1; op[2] = o2; op[3] = o3;
  }
}

extern "C" void kernel_launch(void* const* d_in, const int* in_sizes, int n_in,
                              void* d_out, int out_size, void* d_ws, size_t ws_size,
                              hipStream_t stream) {
  const float* nf  = (const float*)d_in[0];  // [N, 128]
  const float* ew  = (const float*)d_in[1];  // [E, 1]
  const float* W   = (const float*)d_in[2];  // [128, 256]
  const float* b   = (const float*)d_in[3];  // [128]
  const int*   src = (const int*)d_in[4];    // [E]
  const int*   dst = (const int*)d_in[5];    // [E]
  float* out = (float*)d_out;                // [N, 128] f32

  // workspace layout (~45 MB of ~256 MiB ws), 16B-aligned offsets
  char* ws = (char*)d_ws;
  char* wtS  = ws;                                     // 65,536
  char* y1   = wtS + (size_t)WGN * 16;                 // 12,800,000
  char* y2   = y1 + (size_t)N_NODES * DIM * 2;         // 12,800,000
  unsigned* srcw = (unsigned*)(y2 + (size_t)N_NODES * DIM * 2); // 12,800,000
  int* deg   = (int*)(srcw + (size_t)N_NODES * BCAP);  // 200,000
  int* gcnt  = deg + N_NODES;                          // 392 (+pad)
  uint2* binbuf = (uint2*)((char*)(gcnt + 128));       // 98*8192*8 = 6,422,528

  k_zero_wts<<<ZERO_BLOCKS, 256, 0, stream>>>(deg, gcnt, W, (uint4*)wtS);
  k_gemm_p1<<<K1_BLOCKS, 256, 0, stream>>>(
      dst, src, ew, gcnt, binbuf, nf, (const uint4*)wtS, b,
      (unsigned short*)y1, (unsigned short*)y2);
  k_p2<<<BINS, 256, 0, stream>>>(gcnt, binbuf, deg, srcw);
  k_gather<<<N_NODES / 4, 256, 0, stream>>>(
      (const uint4*)y1, (const uint4*)y2, deg, srcw, (float4*)out);
}

// Round 28
// 77.611 us; speedup vs baseline: 1.1393x; 1.1393x over previous
//
#include <hip/hip_runtime.h>

#define N_NODES 50000
#define N_EDGES 600000
#define DIM 128
#define WGN (256 * 128 / 8)                   // 4096 granules of 8 bf16
#define GEMM_PAIRS ((N_NODES + 63) / 64)      // 782 node-tiles (x2 j-halves)
#define HIST_SLICES ((N_EDGES + 255) / 256)   // 2344
#define K1_BLOCKS (GEMM_PAIRS * 5)            // 3910: {g,g,h,h,h} per group
#define ZERO_BLOCKS ((N_NODES + 255) / 256)   // 196
#define BCAP 64                               // rank planes (max deg ~35)

typedef __attribute__((ext_vector_type(8))) short short8;
typedef __attribute__((ext_vector_type(4))) float f32x4;

__device__ __forceinline__ unsigned bf16rne(float f) {
  unsigned x = __float_as_uint(f);
  x += 0x7fffu + ((x >> 16) & 1u);
  return x >> 16;
}

__device__ __forceinline__ uint2 pack4(float4 v) {
  uint2 o;
  o.x = bf16rne(v.x) | (bf16rne(v.y) << 16);
  o.y = bf16rne(v.z) | (bf16rne(v.w) << 16);
  return o;
}

__device__ __forceinline__ void fma8(float* a, uint4 v, float w) {
  a[0] += __uint_as_float(v.x << 16) * w;
  a[1] += __uint_as_float(v.x & 0xffff0000u) * w;
  a[2] += __uint_as_float(v.y << 16) * w;
  a[3] += __uint_as_float(v.y & 0xffff0000u) * w;
  a[4] += __uint_as_float(v.z << 16) * w;
  a[5] += __uint_as_float(v.z & 0xffff0000u) * w;
  a[6] += __uint_as_float(v.w << 16) * w;
  a[7] += __uint_as_float(v.w & 0xffff0000u) * w;
}

// ---------------------------------------------------------------------------
// K0: deg = 0 + wtS fragment pack (tiny).
// wtS layout (r19): fragment (jb,ks) contiguous 1KB, lane (lg*16+l16)*16B.
// ---------------------------------------------------------------------------
__global__ __launch_bounds__(256) void k_zero_wts(
    int* __restrict__ deg, const float* __restrict__ Wf,
    uint4* __restrict__ wtS) {
  int gid = blockIdx.x * 256 + threadIdx.x;
  if (gid < N_NODES) deg[gid] = 0;
  if (gid < WGN) {
    int j = gid >> 4, cb = gid & 15;
    int jr = (j < 128) ? j : (j - 128);
    int c0 = ((j < 128) ? 0 : 128) + cb * 8;
    const float4* s = reinterpret_cast<const float4*>(Wf + (size_t)jr * 256 + c0);
    uint2 lo = pack4(s[0]);
    uint2 hi = pack4(s[1]);
    int jb = j >> 4, l16 = j & 15, ks = cb >> 2, lg = cb & 3;
    wtS[((jb * 4 + ks) * 64) + lg * 16 + l16] = make_uint4(lo.x, lo.y, hi.x, hi.y);
  }
}

// ---------------------------------------------------------------------------
// K1: STRIPED gemm + histscat {g,g,h,h,h} (r23/r25-proven co-residency).
// r28: RANK-MAJOR bucket store — srcw[rk*N + d] instead of srcw[d*64 + rk].
// Mechanism: ranks fill 0,1,2,... over the dispatch, so in-flight writes
// cluster in a few 200KB rank-planes (L2/L3-resident) where partial lines
// accumulate ~16 merges before eviction — vs the node-major layout whose
// instantaneous write set spans all 12.8MB (no merge window; the invariant
// ~41us wall across r5/r24/r26/r27).
// gemm (subs 0,1): r25 body — A from nf f32 coalesced + in-reg cvt ->
// swizzled LDS; W via wtS fragment blocks; packed 8B epilogue.
// ---------------------------------------------------------------------------
__global__ __launch_bounds__(256) void k_gemm_histscat(
    const int* __restrict__ dst, const int* __restrict__ src,
    const float* __restrict__ ew, int* __restrict__ deg,
    unsigned* __restrict__ srcw,
    const float* __restrict__ nf, const uint4* __restrict__ wtS,
    const float* __restrict__ bias,
    unsigned short* __restrict__ y1, unsigned short* __restrict__ y2) {
  __shared__ char As[16384];          // 64 rows x 16 granules(16B bf16), swizzled
  const int grp = blockIdx.x / 5;
  const int sub = blockIdx.x % 5;

  if (sub >= 2) {
    // ---- histscat slice: rank-major store ----
    int hb = grp * 3 + (sub - 2);
    if (hb < HIST_SLICES) {
      int e = hb * 256 + threadIdx.x;
      if (e < N_EDGES) {
        int d = dst[e];
        int rk = atomicAdd(&deg[d], 1);
        unsigned wq = (unsigned)rintf(ew[e] * 65535.0f);
        srcw[(size_t)rk * N_NODES + d] = (unsigned)src[e] | (wq << 16);
      }
    }
    return;
  }

  // ---- gemm: 64 nodes x 128 j (jsel half) ----
  const int node0 = grp * 64;
  const int jsel = sub;               // 0 -> Y1, 1 -> Y2+bias
  const int tid = threadIdx.x;

  // stage A from f32: 2048 float4, 8 coalesced/thread, in-reg bf16 cvt
#pragma unroll
  for (int i = 0; i < 8; ++i) {
    int G = tid + i * 256;
    int r = G >> 5, c = G & 31;       // row, float4-column
    int node = node0 + r;
    if (node > N_NODES - 1) node = N_NODES - 1;   // tail: masked at store
    float4 v = *reinterpret_cast<const float4*>(nf + (size_t)node * DIM + c * 4);
    uint2 p = pack4(v);
    int g = c >> 1, half = c & 1;
    *reinterpret_cast<uint2*>(As + r * 256 + ((g ^ (r & 7)) * 16) + half * 8) = p;
  }
  __syncthreads();

  const int lane = tid & 63;
  const int wv = tid >> 6;            // wave -> 32 j of this 128-half
  const int l16 = lane & 15, lg = lane >> 4;

  f32x4 acc[4][2] = {};   // [m: node frag][n: j frag]
#pragma unroll
  for (int ks = 0; ks < 4; ++ks) {           // K = 128 = 4 x 32
    short8 anf[4], awt[2];
#pragma unroll
    for (int m = 0; m < 4; ++m) {
      int r = m * 16 + l16;
      int g = ks * 4 + lg;
      anf[m] = *reinterpret_cast<const short8*>(As + r * 256 + ((g ^ (r & 7)) * 16));
    }
#pragma unroll
    for (int n = 0; n < 2; ++n) {
      int jb = jsel * 8 + wv * 2 + n;        // global 16-j fragment index
      const uint4* fp = wtS + (jb * 4 + ks) * 64 + lane;
      uint4 v = *fp;
      awt[n] = *reinterpret_cast<const short8*>(&v);
    }
#pragma unroll
    for (int m = 0; m < 4; ++m)
#pragma unroll
      for (int n = 0; n < 2; ++n)
        acc[m][n] = __builtin_amdgcn_mfma_f32_16x16x32_bf16(awt[n], anf[m], acc[m][n], 0, 0, 0);
  }

  // epilogue: per (m,n) one packed 8B store of 4 consecutive j (r14)
  unsigned short* yb = jsel ? y2 : y1;
#pragma unroll
  for (int n = 0; n < 2; ++n) {
    int jb = (wv * 2 + n) * 16 + lg * 4;     // j within the 128-half
    float4 bv = make_float4(0.f, 0.f, 0.f, 0.f);
    if (jsel) bv = *reinterpret_cast<const float4*>(bias + jb);
#pragma unroll
    for (int m = 0; m < 4; ++m) {
      int node = node0 + m * 16 + l16;
      if (node >= N_NODES) continue;
      uint2 st;
      st.x = bf16rne(acc[m][n][0] + bv.x) | (bf16rne(acc[m][n][1] + bv.y) << 16);
      st.y = bf16rne(acc[m][n][2] + bv.z) | (bf16rne(acc[m][n][3] + bv.w) << 16);
      *reinterpret_cast<uint2*>(yb + (size_t)node * 128 + jb) = st;
    }
  }
}

// ---------------------------------------------------------------------------
// K2: gather-final over rank-major planes: entry j of node = srcw[j*N+node].
// Group g's 8 lanes broadcast-read one word; the block's 4 consecutive
// nodes share lines across waves (node*4B adjacent within a plane).
// out[n] = (sum_e w_e * Y1[src_e]) / max(deg,1) + Y2[n]   (f32 write)
// ---------------------------------------------------------------------------
__global__ __launch_bounds__(256) void k_gather(
    const uint4* __restrict__ y1q,   // [N][16] granules of 8 bf16
    const uint4* __restrict__ y2q,
    const int* __restrict__ deg, const unsigned* __restrict__ srcw,
    float4* __restrict__ out4) {
  int node = blockIdx.x * 4 + (threadIdx.x >> 6);
  int lane = threadIdx.x & 63;
  int g = lane >> 3;          // edge group 0..7
  int c = lane & 7;           // 32B chunk 0..7
  int dg = deg[node];

  float a[16];
#pragma unroll
  for (int k = 0; k < 16; ++k) a[k] = 0.f;

  for (int j = g; j < dg; j += 8) {
    unsigned q = srcw[(size_t)j * N_NODES + node];
    float w = (float)(q >> 16) * (1.0f / 65535.0f);
    const uint4* rp = y1q + (size_t)(q & 0xffffu) * 16 + c * 2;
    uint4 v0 = rp[0];
    uint4 v1 = rp[1];
    fma8(a, v0, w);
    fma8(a + 8, v1, w);
  }
#pragma unroll
  for (int k = 0; k < 16; ++k) {
    a[k] += __shfl_xor(a[k], 8);
    a[k] += __shfl_xor(a[k], 16);
    a[k] += __shfl_xor(a[k], 32);
  }
  if (g == 0) {
    float inv = 1.0f / (float)max(dg, 1);
    uint4 u0 = y2q[(size_t)node * 16 + c * 2];
    uint4 u1 = y2q[(size_t)node * 16 + c * 2 + 1];
    float4 o0, o1, o2, o3;
    o0.x = a[0] * inv + __uint_as_float(u0.x << 16);
    o0.y = a[1] * inv + __uint_as_float(u0.x & 0xffff0000u);
    o0.z = a[2] * inv + __uint_as_float(u0.y << 16);
    o0.w = a[3] * inv + __uint_as_float(u0.y & 0xffff0000u);
    o1.x = a[4] * inv + __uint_as_float(u0.z << 16);
    o1.y = a[5] * inv + __uint_as_float(u0.z & 0xffff0000u);
    o1.z = a[6] * inv + __uint_as_float(u0.w << 16);
    o1.w = a[7] * inv + __uint_as_float(u0.w & 0xffff0000u);
    o2.x = a[8] * inv + __uint_as_float(u1.x << 16);
    o2.y = a[9] * inv + __uint_as_float(u1.x & 0xffff0000u);
    o2.z = a[10] * inv + __uint_as_float(u1.y << 16);
    o2.w = a[11] * inv + __uint_as_float(u1.y & 0xffff0000u);
    o3.x = a[12] * inv + __uint_as_float(u1.z << 16);
    o3.y = a[13] * inv + __uint_as_float(u1.z & 0xffff0000u);
    o3.z = a[14] * inv + __uint_as_float(u1.w << 16);
    o3.w = a[15] * inv + __uint_as_float(u1.w & 0xffff0000u);
    float4* op = out4 + (size_t)node * 32 + c * 4;
    op[0] = o0; op[1] = o1; op[2] = o2; op[3] = o3;
  }
}

extern "C" void kernel_launch(void* const* d_in, const int* in_sizes, int n_in,
                              void* d_out, int out_size, void* d_ws, size_t ws_size,
                              hipStream_t stream) {
  const float* nf  = (const float*)d_in[0];  // [N, 128]
  const float* ew  = (const float*)d_in[1];  // [E, 1]
  const float* W   = (const float*)d_in[2];  // [128, 256]
  const float* b   = (const float*)d_in[3];  // [128]
  const int*   src = (const int*)d_in[4];    // [E]
  const int*   dst = (const int*)d_in[5];    // [E]
  float* out = (float*)d_out;                // [N, 128] f32

  // workspace layout (~38.7 MB of ~256 MiB ws), 16B-aligned offsets
  char* ws = (char*)d_ws;
  char* wtS  = ws;                                     // 65,536
  char* y1   = wtS + (size_t)WGN * 16;                 // 12,800,000
  char* y2   = y1 + (size_t)N_NODES * DIM * 2;         // 12,800,000
  unsigned* srcw = (unsigned*)(y2 + (size_t)N_NODES * DIM * 2); // 12,800,000
  int*  deg  = (int*)(srcw + (size_t)N_NODES * BCAP);  // 200,000

  k_zero_wts<<<ZERO_BLOCKS, 256, 0, stream>>>(deg, W, (uint4*)wtS);
  k_gemm_histscat<<<K1_BLOCKS, 256, 0, stream>>>(
      dst, src, ew, deg, srcw, nf, (const uint4*)wtS, b,
      (unsigned short*)y1, (unsigned short*)y2);
  k_gather<<<N_NODES / 4, 256, 0, stream>>>(
      (const uint4*)y1, (const uint4*)y2, deg, srcw, (float4*)out);
}

// Round 29
// 77.351 us; speedup vs baseline: 1.1431x; 1.0034x over previous
//
#include <hip/hip_runtime.h>

#define N_NODES 50000
#define N_EDGES 600000
#define DIM 128
#define WGN (256 * 128 / 8)                   // 4096 granules of 8 bf16
#define GEMM_PAIRS ((N_NODES + 63) / 64)      // 782 node-tiles (x2 j-halves)
#define HIST_SLICES ((N_EDGES + 255) / 256)   // 2344
#define K2_BLOCKS (GEMM_PAIRS * 5)            // 3910: {g,g,h,h,h} per group
#define ZERO_BLOCKS ((N_NODES + 255) / 256)   // 196
#define BCAP 64                               // bucket capacity (max deg ~35)

typedef __attribute__((ext_vector_type(8))) short short8;
typedef __attribute__((ext_vector_type(4))) float f32x4;

__device__ __forceinline__ unsigned bf16rne(float f) {
  unsigned x = __float_as_uint(f);
  x += 0x7fffu + ((x >> 16) & 1u);
  return x >> 16;
}

__device__ __forceinline__ uint2 pack4(float4 v) {
  uint2 o;
  o.x = bf16rne(v.x) | (bf16rne(v.y) << 16);
  o.y = bf16rne(v.z) | (bf16rne(v.w) << 16);
  return o;
}

__device__ __forceinline__ void fma8(float* a, uint4 v, float w) {
  a[0] += __uint_as_float(v.x << 16) * w;
  a[1] += __uint_as_float(v.x & 0xffff0000u) * w;
  a[2] += __uint_as_float(v.y << 16) * w;
  a[3] += __uint_as_float(v.y & 0xffff0000u) * w;
  a[4] += __uint_as_float(v.z << 16) * w;
  a[5] += __uint_as_float(v.z & 0xffff0000u) * w;
  a[6] += __uint_as_float(v.w << 16) * w;
  a[7] += __uint_as_float(v.w & 0xffff0000u) * w;
}

// ---------------------------------------------------------------------------
// K0: deg = 0 + wtS fragment pack (tiny).
// wtS layout (r19): fragment (jb,ks) contiguous 1KB, lane (lg*16+l16)*16B.
// ---------------------------------------------------------------------------
__global__ __launch_bounds__(256) void k_zero_wts(
    int* __restrict__ deg, const float* __restrict__ Wf,
    uint4* __restrict__ wtS) {
  int gid = blockIdx.x * 256 + threadIdx.x;
  if (gid < N_NODES) deg[gid] = 0;
  if (gid < WGN) {
    int j = gid >> 4, cb = gid & 15;
    int jr = (j < 128) ? j : (j - 128);
    int c0 = ((j < 128) ? 0 : 128) + cb * 8;
    const float4* s = reinterpret_cast<const float4*>(Wf + (size_t)jr * 256 + c0);
    uint2 lo = pack4(s[0]);
    uint2 hi = pack4(s[1]);
    int jb = j >> 4, l16 = j & 15, ks = cb >> 2, lg = cb & 3;
    wtS[((jb * 4 + ks) * 64) + lg * 16 + l16] = make_uint4(lo.x, lo.y, hi.x, hi.y);
  }
}

// ---------------------------------------------------------------------------
// K1: STRIPED gemm + histscat {g,g,h,h,h} (r23-proven co-residency; the
// edge-build phase is an empirically invariant ~41-46us across 7 variants —
// the gemm rides entirely under it).
// gemm (subs 0,1): A staged from nf F32 with coalesced float4 loads +
// in-register bf16 cvt -> swizzled LDS; W via wtS fragment blocks (L2-hot,
// lane-coalesced); packed 8B transposed-C epilogue.
// histscat (subs 2..4): padded-bucket CSR — slot = dst*BCAP + atomic rank.
// ---------------------------------------------------------------------------
__global__ __launch_bounds__(256) void k_gemm_histscat(
    const int* __restrict__ dst, const int* __restrict__ src,
    const float* __restrict__ ew, int* __restrict__ deg,
    unsigned* __restrict__ srcw,
    const float* __restrict__ nf, const uint4* __restrict__ wtS,
    const float* __restrict__ bias,
    unsigned short* __restrict__ y1, unsigned short* __restrict__ y2) {
  __shared__ char As[16384];          // 64 rows x 16 granules(16B bf16), swizzled
  const int grp = blockIdx.x / 5;
  const int sub = blockIdx.x % 5;

  if (sub >= 2) {
    // ---- histscat slice ----
    int hb = grp * 3 + (sub - 2);
    if (hb < HIST_SLICES) {
      int e = hb * 256 + threadIdx.x;
      if (e < N_EDGES) {
        int d = dst[e];
        int rk = atomicAdd(&deg[d], 1);
        unsigned wq = (unsigned)rintf(ew[e] * 65535.0f);
        srcw[d * BCAP + rk] = (unsigned)src[e] | (wq << 16);
      }
    }
    return;
  }

  // ---- gemm: 64 nodes x 128 j (jsel half) ----
  const int node0 = grp * 64;
  const int jsel = sub;               // 0 -> Y1, 1 -> Y2+bias
  const int tid = threadIdx.x;

  // stage A from f32: 2048 float4, 8 coalesced/thread, in-reg bf16 cvt
#pragma unroll
  for (int i = 0; i < 8; ++i) {
    int G = tid + i * 256;
    int r = G >> 5, c = G & 31;       // row, float4-column
    int node = node0 + r;
    if (node > N_NODES - 1) node = N_NODES - 1;   // tail: masked at store
    float4 v = *reinterpret_cast<const float4*>(nf + (size_t)node * DIM + c * 4);
    uint2 p = pack4(v);
    int g = c >> 1, half = c & 1;
    *reinterpret_cast<uint2*>(As + r * 256 + ((g ^ (r & 7)) * 16) + half * 8) = p;
  }
  __syncthreads();

  const int lane = tid & 63;
  const int wv = tid >> 6;            // wave -> 32 j of this 128-half
  const int l16 = lane & 15, lg = lane >> 4;

  f32x4 acc[4][2] = {};   // [m: node frag][n: j frag]
#pragma unroll
  for (int ks = 0; ks < 4; ++ks) {           // K = 128 = 4 x 32
    short8 anf[4], awt[2];
#pragma unroll
    for (int m = 0; m < 4; ++m) {
      int r = m * 16 + l16;
      int g = ks * 4 + lg;
      anf[m] = *reinterpret_cast<const short8*>(As + r * 256 + ((g ^ (r & 7)) * 16));
    }
#pragma unroll
    for (int n = 0; n < 2; ++n) {
      int jb = jsel * 8 + wv * 2 + n;        // global 16-j fragment index
      const uint4* fp = wtS + (jb * 4 + ks) * 64 + lane;
      uint4 v = *fp;
      awt[n] = *reinterpret_cast<const short8*>(&v);
    }
#pragma unroll
    for (int m = 0; m < 4; ++m)
#pragma unroll
      for (int n = 0; n < 2; ++n)
        acc[m][n] = __builtin_amdgcn_mfma_f32_16x16x32_bf16(awt[n], anf[m], acc[m][n], 0, 0, 0);
  }

  // epilogue: per (m,n) one packed 8B store of 4 consecutive j (r14)
  unsigned short* yb = jsel ? y2 : y1;
#pragma unroll
  for (int n = 0; n < 2; ++n) {
    int jb = (wv * 2 + n) * 16 + lg * 4;     // j within the 128-half
    float4 bv = make_float4(0.f, 0.f, 0.f, 0.f);
    if (jsel) bv = *reinterpret_cast<const float4*>(bias + jb);
#pragma unroll
    for (int m = 0; m < 4; ++m) {
      int node = node0 + m * 16 + l16;
      if (node >= N_NODES) continue;
      uint2 st;
      st.x = bf16rne(acc[m][n][0] + bv.x) | (bf16rne(acc[m][n][1] + bv.y) << 16);
      st.y = bf16rne(acc[m][n][2] + bv.z) | (bf16rne(acc[m][n][3] + bv.w) << 16);
      *reinterpret_cast<uint2*>(yb + (size_t)node * 128 + jb) = st;
    }
  }
}

// ---------------------------------------------------------------------------
// K2: gather-final over padded buckets (off = node*64, no cursor).
// out[n] = (sum_e w_e * Y1[src_e]) / max(deg,1) + Y2[n]   (f32 write)
// wave = 8 edge-groups x 8 lanes; lane c holds 32B chunk c of the 256B row.
// ---------------------------------------------------------------------------
__global__ __launch_bounds__(256) void k_gather(
    const uint4* __restrict__ y1q,   // [N][16] granules of 8 bf16
    const uint4* __restrict__ y2q,
    const int* __restrict__ deg, const unsigned* __restrict__ srcw,
    float4* __restrict__ out4) {
  int node = blockIdx.x * 4 + (threadIdx.x >> 6);
  int lane = threadIdx.x & 63;
  int g = lane >> 3;          // edge group 0..7
  int c = lane & 7;           // 32B chunk 0..7
  int dg = deg[node];
  const unsigned* bucket = srcw + (size_t)node * BCAP;

  float a[16];
#pragma unroll
  for (int k = 0; k < 16; ++k) a[k] = 0.f;

  for (int j = g; j < dg; j += 8) {
    unsigned q = bucket[j];
    float w = (float)(q >> 16) * (1.0f / 65535.0f);
    const uint4* rp = y1q + (size_t)(q & 0xffffu) * 16 + c * 2;
    uint4 v0 = rp[0];
    uint4 v1 = rp[1];
    fma8(a, v0, w);
    fma8(a + 8, v1, w);
  }
#pragma unroll
  for (int k = 0; k < 16; ++k) {
    a[k] += __shfl_xor(a[k], 8);
    a[k] += __shfl_xor(a[k], 16);
    a[k] += __shfl_xor(a[k], 32);
  }
  if (g == 0) {
    float inv = 1.0f / (float)max(dg, 1);
    uint4 u0 = y2q[(size_t)node * 16 + c * 2];
    uint4 u1 = y2q[(size_t)node * 16 + c * 2 + 1];
    float4 o0, o1, o2, o3;
    o0.x = a[0] * inv + __uint_as_float(u0.x << 16);
    o0.y = a[1] * inv + __uint_as_float(u0.x & 0xffff0000u);
    o0.z = a[2] * inv + __uint_as_float(u0.y << 16);
    o0.w = a[3] * inv + __uint_as_float(u0.y & 0xffff0000u);
    o1.x = a[4] * inv + __uint_as_float(u0.z << 16);
    o1.y = a[5] * inv + __uint_as_float(u0.z & 0xffff0000u);
    o1.z = a[6] * inv + __uint_as_float(u0.w << 16);
    o1.w = a[7] * inv + __uint_as_float(u0.w & 0xffff0000u);
    o2.x = a[8] * inv + __uint_as_float(u1.x << 16);
    o2.y = a[9] * inv + __uint_as_float(u1.x & 0xffff0000u);
    o2.z = a[10] * inv + __uint_as_float(u1.y << 16);
    o2.w = a[11] * inv + __uint_as_float(u1.y & 0xffff0000u);
    o3.x = a[12] * inv + __uint_as_float(u1.z << 16);
    o3.y = a[13] * inv + __uint_as_float(u1.z & 0xffff0000u);
    o3.z = a[14] * inv + __uint_as_float(u1.w << 16);
    o3.w = a[15] * inv + __uint_as_float(u1.w & 0xffff0000u);
    float4* op = out4 + (size_t)node * 32 + c * 4;
    op[0] = o0; op[1] = o1; op[2] = o2; op[3] = o3;
  }
}

extern "C" void kernel_launch(void* const* d_in, const int* in_sizes, int n_in,
                              void* d_out, int out_size, void* d_ws, size_t ws_size,
                              hipStream_t stream) {
  const float* nf  = (const float*)d_in[0];  // [N, 128]
  const float* ew  = (const float*)d_in[1];  // [E, 1]
  const float* W   = (const float*)d_in[2];  // [128, 256]
  const float* b   = (const float*)d_in[3];  // [128]
  const int*   src = (const int*)d_in[4];    // [E]
  const int*   dst = (const int*)d_in[5];    // [E]
  float* out = (float*)d_out;                // [N, 128] f32

  // workspace layout (~38.7 MB of ~256 MiB ws), 16B-aligned offsets
  char* ws = (char*)d_ws;
  char* wtS  = ws;                                     // 65,536
  char* y1   = wtS + (size_t)WGN * 16;                 // 12,800,000
  char* y2   = y1 + (size_t)N_NODES * DIM * 2;         // 12,800,000
  unsigned* srcw = (unsigned*)(y2 + (size_t)N_NODES * DIM * 2); // 12,800,000
  int*  deg  = (int*)(srcw + (size_t)N_NODES * BCAP);  // 200,000

  k_zero_wts<<<ZERO_BLOCKS, 256, 0, stream>>>(deg, W, (uint4*)wtS);
  k_gemm_histscat<<<K2_BLOCKS, 256, 0, stream>>>(
      dst, src, ew, deg, srcw, nf, (const uint4*)wtS, b,
      (unsigned short*)y1, (unsigned short*)y2);
  k_gather<<<N_NODES / 4, 256, 0, stream>>>(
      (const uint4*)y1, (const uint4*)y2, deg, srcw, (float4*)out);
}